// Round 4
// baseline (996.457 us; speedup 1.0000x reference)
//
#include <hip/hip_runtime.h>

typedef unsigned short u16;
typedef __attribute__((ext_vector_type(4))) float f4;
typedef __attribute__((ext_vector_type(4))) float f32x4;
typedef __attribute__((ext_vector_type(8))) short short8;
typedef __attribute__((ext_vector_type(4))) unsigned short u16x4;

#define DEV static __device__ __forceinline__

DEV u16 f2bf(float f) {                    // round-to-nearest-even f32->bf16
  unsigned u = __float_as_uint(f);
  u += 0x7fffu + ((u >> 16) & 1u);
  return (u16)(u >> 16);
}
DEV float siluf(float z) { return z / (1.f + __expf(-z)); }

// async global->LDS, 16B per lane (wave-uniform LDS base + lane*16)
DEV void gload16(const u16* g, const u16* l) {
  __builtin_amdgcn_global_load_lds(
      (const __attribute__((address_space(1))) unsigned int*)(unsigned long long)g,
      (__attribute__((address_space(3))) unsigned int*)(unsigned int)(unsigned long long)l,
      16, 0, 0);
}

// ---------------- batched weight converts (8 mamba weights + proj_w) ----------------
struct CvtArgs {
  const float* src[9];
  u16* dst[9];
  int bstart[10];
  int nq[9];
};

DEV void cvt_plain(const float* __restrict__ s, u16* __restrict__ d, int q, int nq) {
  if (q < nq) {
    f4 v = ((const f4*)s)[q];
    u16x4 o;
#pragma unroll
    for (int e = 0; e < 4; ++e) o[e] = f2bf(v[e]);
    ((u16x4*)d)[q] = o;
  }
}
// dt_w [768][24] f32 -> [768][32] bf16 zero-padded
DEV void cvt_pad(const float* __restrict__ s, u16* __restrict__ d, int q, int nq) {
  if (q < nq) {
    int e0 = q * 4, n = e0 >> 5, k = e0 & 31;
    u16x4 o;
#pragma unroll
    for (int e = 0; e < 4; ++e) {
      int kk = k + e;
      float v = (kk < 24) ? s[n * 24 + kk] : 0.f;
      o[e] = f2bf(v);
    }
    ((u16x4*)d)[q] = o;
  }
}

__global__ void k_cvtmulti(CvtArgs a) {
  int b = blockIdx.x;
  int i = 0;
#pragma unroll
  for (int j = 1; j < 9; ++j) i += (b >= a.bstart[j]);
#pragma unroll
  for (int j = 0; j < 9; ++j) {
    if (i == j) {
      int q = (b - a.bstart[j]) * 256 + threadIdx.x;
      if (j == 2 || j == 6) cvt_pad(a.src[j], a.dst[j], q, a.nq[j]);
      else                  cvt_plain(a.src[j], a.dst[j], q, a.nq[j]);
    }
  }
}

// ---------------- conv weight transpose [O][I][3] -> [I][3][O] ----------------
__global__ void k_wtrans(const float* __restrict__ in, float* __restrict__ out, int O, int I) {
  int n = O * I * 3;
  for (int g = blockIdx.x * blockDim.x + threadIdx.x; g < n; g += gridDim.x * blockDim.x) {
    int o = g / (I * 3);
    int rem = g - o * (I * 3);
    out[rem * O + o] = in[g];
  }
}

// ---------------- audio conv1: [2,80,1024] -> relu -> a1t [2,1024,192] ----------------
__global__ __launch_bounds__(192) void k_conv1(const float* __restrict__ audio,
    const float* __restrict__ w1t, const float* __restrict__ b1, float* __restrict__ a1t) {
  __shared__ float s[80][18];
  int bx = blockIdx.x;
  int b = bx >> 6, l0 = (bx & 63) << 4;
  int tid = threadIdx.x;
  for (int i = tid; i < 80 * 18; i += 192) {
    int ci = i / 18, dl = i - ci * 18;
    int l = l0 + dl - 1;
    s[ci][dl] = (l >= 0 && l < 1024) ? audio[(b * 80 + ci) * 1024 + l] : 0.f;
  }
  __syncthreads();
  int co = tid;
  float acc[16];
  float bias = b1[co];
#pragma unroll
  for (int i = 0; i < 16; ++i) acc[i] = bias;
  for (int ci = 0; ci < 80; ++ci) {
#pragma unroll
    for (int j = 0; j < 3; ++j) {
      float w = w1t[(ci * 3 + j) * 192 + co];
#pragma unroll
      for (int ls = 0; ls < 16; ++ls) acc[ls] = fmaf(s[ci][ls + j], w, acc[ls]);
    }
  }
#pragma unroll
  for (int ls = 0; ls < 16; ++ls) {
    float v = acc[ls] > 0.f ? acc[ls] : 0.f;
    a1t[(b * 1024 + l0 + ls) * 192 + co] = v;
  }
}

// ---------------- audio conv2: a1t -> bf16 X rows [b*2048 + l][384] ----------------
__global__ __launch_bounds__(384) void k_conv2b(const float* __restrict__ a1t,
    const float* __restrict__ w2t, const float* __restrict__ b2, u16* __restrict__ Xb) {
  __shared__ float s[10][192];
  int bx = blockIdx.x;
  int b = bx >> 7, l0 = (bx & 127) << 3;
  int tid = threadIdx.x;
  for (int i = tid; i < 10 * 192; i += 384) {
    int dl = i / 192, ci = i - dl * 192;
    int l = l0 + dl - 1;
    s[dl][ci] = (l >= 0 && l < 1024) ? a1t[(b * 1024 + l) * 192 + ci] : 0.f;
  }
  __syncthreads();
  int co = tid;
  float acc[8];
  float bias = b2[co];
#pragma unroll
  for (int i = 0; i < 8; ++i) acc[i] = bias;
  for (int ci = 0; ci < 192; ++ci) {
#pragma unroll
    for (int j = 0; j < 3; ++j) {
      float w = w2t[(ci * 3 + j) * 384 + co];
#pragma unroll
      for (int ls = 0; ls < 8; ++ls) acc[ls] = fmaf(s[ls + j][ci], w, acc[ls]);
    }
  }
#pragma unroll
  for (int ls = 0; ls < 8; ++ls)
    Xb[((size_t)(b * 2048 + l0 + ls)) * 384 + co] = f2bf(acc[ls]);
}

// ---------------- text embedding gather -> bf16 X rows [b*2048+1024+t] ----------------
__global__ void k_embedb(const int* __restrict__ tok, const float* __restrict__ emb,
                         u16* __restrict__ Xb) {
  int gid = blockIdx.x * blockDim.x + threadIdx.x;
  if (gid >= 2 * 1024 * 96) return;
  int q = gid % 96;
  int rt = gid / 96;
  int b = rt >> 10, t = rt & 1023;
  int tk = tok[b * 1024 + t];
  f4 v = *(const f4*)(emb + (size_t)tk * 384 + q * 4);
  u16x4 o;
#pragma unroll
  for (int e = 0; e < 4; ++e) o[e] = f2bf(v[e]);
  *(u16x4*)(Xb + ((size_t)(b * 2048 + 1024 + t)) * 384 + q * 4) = o;
}

// ---------------- depthwise causal conv (K=4) + silu: dual f32+bf16 output ----------------
__global__ void k_dwconv2(const float* __restrict__ xz, const float* __restrict__ cw,
                          const float* __restrict__ cb, float* __restrict__ xif,
                          u16* __restrict__ xib) {
  int gid = blockIdx.x * blockDim.x + threadIdx.x;
  if (gid >= 4096 * 192) return;
  int d4 = gid % 192;
  int row = gid / 192;
  int b = row >> 11, l = row & 2047;
  int d = d4 * 4;
  f4 cw0 = *(const f4*)(cw + d * 4);
  f4 cw1 = *(const f4*)(cw + d * 4 + 4);
  f4 cw2 = *(const f4*)(cw + d * 4 + 8);
  f4 cw3 = *(const f4*)(cw + d * 4 + 12);
  f4 acc = *(const f4*)(cb + d);
#pragma unroll
  for (int j = 0; j < 4; ++j) {
    int lj = l - 3 + j;
    if (lj >= 0) {
      f4 v = *(const f4*)(xz + ((size_t)(b * 2048 + lj)) * 1536 + d);
      acc[0] = fmaf(v[0], cw0[j], acc[0]);
      acc[1] = fmaf(v[1], cw1[j], acc[1]);
      acc[2] = fmaf(v[2], cw2[j], acc[2]);
      acc[3] = fmaf(v[3], cw3[j], acc[3]);
    }
  }
  f4 o;
  u16x4 ob;
#pragma unroll
  for (int e = 0; e < 4; ++e) { o[e] = siluf(acc[e]); ob[e] = f2bf(o[e]); }
  *(f4*)(xif + (size_t)row * 768 + d) = o;
  *(u16x4*)(xib + (size_t)row * 768 + d) = ob;
}

// ---------------- bf16 MFMA GEMM, 3-buffer LDS + counted-vmcnt pipeline (T3/T4) ----------------
// C[m,n] = act(sum_k A[m,k]*W[n,k] + bias[n]); M mult of TILE, K mult of 32.
// TILE: 128 (4 waves x 64x64) or 64 (4 waves x 32x32). OUTB: 0=f32,1=bf16,2=both.
template <int TILE, int BIAS, int ACT, int OUTB, int SWZ>
__global__ __launch_bounds__(256) void k_gemm3(
    const u16* __restrict__ A, int lda, const u16* __restrict__ W, int ldw,
    const float* __restrict__ bias, float* __restrict__ C, u16* __restrict__ Cb,
    int ldc, int M, int N, int K) {
  constexpr int MF = (TILE == 128) ? 4 : 2;       // 16x16 frags per wave dim
  constexpr int TB = TILE * 32;                   // elems per tile buffer
  constexpr int NLD = (TILE == 128) ? 4 : 2;      // global_load_lds per stage
  __shared__ u16 As[3][TB], Ws[3][TB];
  int bid = blockIdx.x;
  if (SWZ) {
    int nwg = gridDim.x;
    int q = nwg >> 3, r = nwg & 7;
    int xcd = bid & 7, li = bid >> 3;
    bid = (xcd < r ? xcd * (q + 1) : r * (q + 1) + (xcd - r) * q) + li;
  }
  int bm, bn;
  if (TILE == 128) { bm = (bid & 31) << 7; bn = (bid >> 5) << 7; }
  else             { bm = (bid & 63) << 6; bn = (bid >> 6) << 6; }
  int t = threadIdx.x, lane = t & 63, wave = t >> 6;
  int wm0, wn0;
  if (TILE == 128) { wm0 = (wave >> 1) << 6; wn0 = (wave & 1) << 6; }
  else             { wm0 = (wave >> 1) << 5; wn0 = (wave & 1) << 5; }
  int fr = lane & 15, fk = (lane >> 4) << 3;
  int r0 = t >> 2, sl = (t & 3) << 3;             // staging row / 8-elem slot
  const u16* gA0 = A + (size_t)(bm + r0) * lda + sl;
  const u16* gA1 = gA0 + (size_t)64 * lda;
  int n0 = bn + r0;      if (n0 > N - 1) n0 = N - 1;
  int n1 = bn + r0 + 64; if (n1 > N - 1) n1 = N - 1;
  const u16* gW0 = W + (size_t)n0 * ldw + sl;
  const u16* gW1 = W + (size_t)n1 * ldw + sl;
  f32x4 acc[MF][MF] = {};
  int nk = K >> 5;
  auto stage = [&](int buf, int k0) {
    gload16(gA0 + k0, As[buf] + t * 8);
    gload16(gW0 + k0, Ws[buf] + t * 8);
    if (TILE == 128) {
      gload16(gA1 + k0, As[buf] + t * 8 + 2048);
      gload16(gW1 + k0, Ws[buf] + t * 8 + 2048);
    }
  };
  stage(0, 0);
  if (nk > 1) stage(1, 32);
  int cur = 0;
  for (int s = 0; s < nk; ++s) {
    // wait only for the OLDEST stage (stage s); stage s+1 stays in flight (T4)
    if (s < nk - 1) asm volatile("s_waitcnt vmcnt(%0)" :: "i"(NLD) : "memory");
    else            asm volatile("s_waitcnt vmcnt(0)" ::: "memory");
    __builtin_amdgcn_sched_barrier(0);
    __builtin_amdgcn_s_barrier();
    __builtin_amdgcn_sched_barrier(0);
    int nxt2 = (cur == 0) ? 2 : cur - 1;          // (cur+2)%3 — buffer read 2 iters ago
    if (s + 2 < nk) stage(nxt2, (s + 2) << 5);    // prefetch 2 ahead, spans barriers
    short8 af[MF], wf[MF];
#pragma unroll
    for (int mi = 0; mi < MF; ++mi) af[mi] = *(const short8*)&As[cur][(wm0 + mi * 16 + fr) * 32 + fk];
#pragma unroll
    for (int ni = 0; ni < MF; ++ni) wf[ni] = *(const short8*)&Ws[cur][(wn0 + ni * 16 + fr) * 32 + fk];
#pragma unroll
    for (int mi = 0; mi < MF; ++mi)
#pragma unroll
      for (int ni = 0; ni < MF; ++ni)
        acc[mi][ni] = __builtin_amdgcn_mfma_f32_16x16x32_bf16(af[mi], wf[ni], acc[mi][ni], 0, 0, 0);
    cur = (cur == 2) ? 0 : cur + 1;
  }
  int frow = (lane >> 4) << 2;
#pragma unroll
  for (int ni = 0; ni < MF; ++ni) {
    int col = bn + wn0 + ni * 16 + fr;
    if (col < N) {
      float bv = BIAS ? bias[col] : 0.f;
#pragma unroll
      for (int mi = 0; mi < MF; ++mi) {
        int row = bm + wm0 + mi * 16 + frow;
#pragma unroll
        for (int rr = 0; rr < 4; ++rr) {
          float v = acc[mi][ni][rr] + bv;
          if (ACT == 1) v = (v > 20.f) ? v : log1pf(__expf(v));
          size_t o = (size_t)(row + rr) * ldc + col;
          if (OUTB == 0) C[o] = v;
          else if (OUTB == 1) Cb[o] = f2bf(v);
          else { C[o] = v; Cb[o] = f2bf(v); }
        }
      }
    }
  }
}

// ---------------- segmented selective scan ----------------
// 32 segments x 64 t. Pass A: local scan (h0=0) -> Hloc, sum(dt) -> Sdt.
// Pass B: serial combine over segments -> Hini. Pass C: recompute with Hini, emit y.
// wave layout: lane = c*16 + n, 4 channels per wave.
__global__ __launch_bounds__(64) void k_scanA(
    const float* __restrict__ dt, const float* __restrict__ xdbl,
    const float* __restrict__ xi, const float* __restrict__ A_log,
    float* __restrict__ Hloc, float* __restrict__ Sdt) {
  int b = blockIdx.y, seg = blockIdx.z;
  int ch0 = blockIdx.x * 4;
  int tid = threadIdx.x;
  int c = tid >> 4, n = tid & 15;
  int d = ch0 + c;
  float a = -__expf(A_log[d * 16 + n]);
  float h = 0.f, sdt = 0.f;
  size_t row = (size_t)b * 2048 + seg * 64;
#pragma unroll 4
  for (int i = 0; i < 64; ++i, ++row) {
    float dtv = dt[row * 768 + d];
    float xiv = xi[row * 768 + d];
    float Bv = xdbl[row * 56 + 24 + n];
    float da = __expf(dtv * a);
    h = fmaf(da, h, dtv * Bv * xiv);
    sdt += dtv;
  }
  size_t o = (((size_t)b * 32 + seg) * 768 + d) * 16 + n;
  Hloc[o] = h;
  if (n == 0) Sdt[((size_t)b * 32 + seg) * 768 + d] = sdt;
}

__global__ __launch_bounds__(256) void k_scanB(
    const float* __restrict__ Hloc, const float* __restrict__ Sdt,
    const float* __restrict__ A_log, float* __restrict__ Hini) {
  int gid = blockIdx.x * 256 + threadIdx.x;     // 2*768*16 = 24576
  if (gid >= 24576) return;
  int b = gid / 12288;
  int r = gid - b * 12288;
  int d = r >> 4, n = r & 15;
  float a = -__expf(A_log[d * 16 + n]);
  float h = 0.f;
  for (int s = 0; s < 32; ++s) {
    size_t o = (((size_t)b * 32 + s) * 768 + d) * 16 + n;
    Hini[o] = h;
    float P = __expf(a * Sdt[((size_t)b * 32 + s) * 768 + d]);
    h = fmaf(P, h, Hloc[o]);
  }
}

__global__ __launch_bounds__(64) void k_scanC(
    const float* __restrict__ dt, const float* __restrict__ xdbl,
    const float* __restrict__ xi, const float* __restrict__ xz,
    const float* __restrict__ A_log, const float* __restrict__ Dp,
    const float* __restrict__ Hini, u16* __restrict__ y) {
  __shared__ float s_y[64][4];
  int b = blockIdx.y, seg = blockIdx.z;
  int ch0 = blockIdx.x * 4;
  int tid = threadIdx.x;
  int c = tid >> 4, n = tid & 15;
  int d = ch0 + c;
  float a = -__expf(A_log[d * 16 + n]);
  float h = Hini[(((size_t)b * 32 + seg) * 768 + d) * 16 + n];
  size_t row = (size_t)b * 2048 + seg * 64;
#pragma unroll 2
  for (int i = 0; i < 64; ++i, ++row) {
    float dtv = dt[row * 768 + d];
    float xiv = xi[row * 768 + d];
    float Bv = xdbl[row * 56 + 24 + n];
    float Cv = xdbl[row * 56 + 40 + n];
    float da = __expf(dtv * a);
    h = fmaf(da, h, dtv * Bv * xiv);
    float yv = h * Cv;
    yv += __shfl_xor(yv, 1);
    yv += __shfl_xor(yv, 2);
    yv += __shfl_xor(yv, 4);
    yv += __shfl_xor(yv, 8);
    if (n == 0) s_y[i][c] = yv;
  }
  __syncthreads();
  // write 64 rows x 4 channels, one row per lane
  size_t rw = (size_t)b * 2048 + seg * 64 + tid;
  f4 xiv4 = *(const f4*)(xi + rw * 768 + ch0);
  f4 dpv = *(const f4*)(Dp + ch0);
  f4 zv = *(const f4*)(xz + rw * 1536 + 768 + ch0);
  u16x4 ob;
#pragma unroll
  for (int e = 0; e < 4; ++e) {
    float o = (s_y[tid][e] + xiv4[e] * dpv[e]) * siluf(zv[e]);
    ob[e] = f2bf(o);
  }
  *(u16x4*)(y + rw * 768 + ch0) = ob;
}

// =====================================================================================
extern "C" void kernel_launch(void* const* d_in, const int* in_sizes, int n_in,
                              void* d_out, int out_size, void* d_ws, size_t ws_size,
                              hipStream_t stream) {
  const float* audio   = (const float*)d_in[0];
  const int*   tokens  = (const int*)d_in[1];
  const float* conv1_w = (const float*)d_in[2];
  const float* conv1_b = (const float*)d_in[3];
  const float* conv2_w = (const float*)d_in[4];
  const float* conv2_b = (const float*)d_in[5];
  const float* embedw  = (const float*)d_in[6];
  const float* P1[9], *P2[9];
  for (int i = 0; i < 9; ++i) { P1[i] = (const float*)d_in[7 + i]; P2[i] = (const float*)d_in[16 + i]; }
  const float* proj_w = (const float*)d_in[25];
  const float* proj_b = (const float*)d_in[26];
  (void)in_sizes; (void)n_in; (void)out_size; (void)ws_size;

  // ---- arena in d_out (fully overwritten by final GEMM) ----
  float* base = (float*)d_out;
  size_t off = 0;
  auto af = [&](size_t n) { float* p = base + off; off += n; return p; };
  float* xz   = af((size_t)4096 * 1536);
  float* xif  = af((size_t)4096 * 768);
  float* xdbl = af((size_t)4096 * 56);
  float* dtb  = af((size_t)4096 * 768);
  float* a1t  = af((size_t)2 * 1024 * 192);
  float* w1t  = af((size_t)80 * 3 * 192);
  float* w2t  = af((size_t)192 * 3 * 384);
  float* Hloc = af((size_t)2 * 32 * 768 * 16);
  float* Hini = af((size_t)2 * 32 * 768 * 16);
  float* Sdt  = af((size_t)2 * 32 * 768);
  u16* ub = (u16*)(base + off);
  size_t uoff = 0;
  auto au = [&](size_t n) { u16* p = ub + uoff; uoff += n; return p; };
  u16* Xin_b  = au((size_t)4096 * 384);
  u16* Xmid_b = au((size_t)4096 * 384);
  u16* xib    = au((size_t)4096 * 768);
  u16* xdblb  = au((size_t)4096 * 56);
  u16* yb16   = au((size_t)4096 * 768);
  u16* Wi1 = au((size_t)1536 * 384);
  u16* Wx1 = au((size_t)56 * 768);
  u16* Wd1 = au((size_t)768 * 32);
  u16* Wo1 = au((size_t)384 * 768);
  u16* Wi2 = au((size_t)1536 * 384);
  u16* Wx2 = au((size_t)56 * 768);
  u16* Wd2 = au((size_t)768 * 32);
  u16* Wo2 = au((size_t)384 * 768);
  u16* X2b    = (u16*)d_ws;                       // survive final GEMM's d_out writes
  u16* projwb = X2b + (size_t)4096 * 384;

  // ---- one batched weight-convert kernel ----
  CvtArgs ca;
  const float* srcs[9] = {P1[0], P1[3], P1[4], P1[8], P2[0], P2[3], P2[4], P2[8], proj_w};
  u16* dsts[9] = {Wi1, Wx1, Wd1, Wo1, Wi2, Wx2, Wd2, Wo2, projwb};
  int nqs[9] = {147456, 10752, 6144, 73728, 147456, 10752, 6144, 73728, 4824672};
  int cum = 0;
  for (int j = 0; j < 9; ++j) {
    ca.src[j] = srcs[j]; ca.dst[j] = dsts[j]; ca.nq[j] = nqs[j];
    ca.bstart[j] = cum; cum += (nqs[j] + 255) / 256;
  }
  ca.bstart[9] = cum;
  k_cvtmulti<<<dim3(cum), dim3(256), 0, stream>>>(ca);

  // ---- audio frontend + embedding -> Xin_b bf16 ----
  k_wtrans<<<dim3(180), dim3(256), 0, stream>>>(conv1_w, w1t, 192, 80);
  k_wtrans<<<dim3(864), dim3(256), 0, stream>>>(conv2_w, w2t, 384, 192);
  k_conv1<<<dim3(128), dim3(192), 0, stream>>>(audio, w1t, conv1_b, a1t);
  k_conv2b<<<dim3(256), dim3(384), 0, stream>>>(a1t, w2t, conv2_b, Xin_b);
  k_embedb<<<dim3(768), dim3(256), 0, stream>>>(tokens, embedw, Xin_b);

  auto run_mamba = [&](const float* const* P, const u16* Xin, u16* Xout,
                       const u16* Wi, const u16* Wx, const u16* Wd, const u16* Wo) {
    k_gemm3<64, 0, 0, 0, 1><<<dim3(64 * 24), dim3(256), 0, stream>>>(
        Xin, 384, Wi, 384, nullptr, xz, nullptr, 1536, 4096, 1536, 384);
    k_dwconv2<<<dim3(3072), dim3(256), 0, stream>>>(xz, P[1], P[2], xif, xib);
    k_gemm3<64, 0, 0, 2, 1><<<dim3(64 * 1), dim3(256), 0, stream>>>(
        xib, 768, Wx, 768, nullptr, xdbl, xdblb, 56, 4096, 56, 768);
    k_gemm3<64, 1, 1, 0, 1><<<dim3(64 * 12), dim3(256), 0, stream>>>(
        xdblb, 56, Wd, 32, P[5], dtb, nullptr, 768, 4096, 768, 32);
    k_scanA<<<dim3(192, 2, 32), dim3(64), 0, stream>>>(dtb, xdbl, xif, P[6], Hloc, Sdt);
    k_scanB<<<dim3(96), dim3(256), 0, stream>>>(Hloc, Sdt, P[6], Hini);
    k_scanC<<<dim3(192, 2, 32), dim3(64), 0, stream>>>(dtb, xdbl, xif, xz, P[6], P[7], Hini, yb16);
    k_gemm3<64, 0, 0, 1, 1><<<dim3(64 * 6), dim3(256), 0, stream>>>(
        yb16, 768, Wo, 768, nullptr, nullptr, Xout, 384, 4096, 384, 768);
  };
  run_mamba(P1, Xin_b, Xmid_b, Wi1, Wx1, Wd1, Wo1);
  run_mamba(P2, Xmid_b, X2b, Wi2, Wx2, Wd2, Wo2);

  // ---- final projection -> d_out [4096, 50257] f32 (XCD-swizzled) ----
  k_gemm3<128, 1, 0, 0, 1><<<dim3(32 * 393), dim3(256), 0, stream>>>(
      X2b, 384, projwb, 384, proj_b, (float*)d_out, nullptr, 50257, 4096, 50257, 384);
}

// Round 5
// 899.371 us; speedup vs baseline: 1.1079x; 1.1079x over previous
//
#include <hip/hip_runtime.h>

typedef unsigned short u16;
typedef __attribute__((ext_vector_type(4))) float f4;
typedef __attribute__((ext_vector_type(4))) float f32x4;
typedef __attribute__((ext_vector_type(8))) short short8;
typedef __attribute__((ext_vector_type(4))) unsigned short u16x4;

#define DEV static __device__ __forceinline__

DEV u16 f2bf(float f) {                    // round-to-nearest-even f32->bf16
  unsigned u = __float_as_uint(f);
  u += 0x7fffu + ((u >> 16) & 1u);
  return (u16)(u >> 16);
}
DEV float siluf(float z) { return z / (1.f + __expf(-z)); }

// async global->LDS, 16B per lane (wave-uniform LDS base + lane*16)
DEV void gload16(const u16* g, const u16* l) {
  __builtin_amdgcn_global_load_lds(
      (const __attribute__((address_space(1))) unsigned int*)(unsigned long long)g,
      (__attribute__((address_space(3))) unsigned int*)(unsigned int)(unsigned long long)l,
      16, 0, 0);
}

// ---------------- batched weight converts (8 mamba weights + proj_w) ----------------
struct CvtArgs {
  const float* src[9];
  u16* dst[9];
  int bstart[10];
  int nq[9];
};

DEV void cvt_plain(const float* __restrict__ s, u16* __restrict__ d, int q, int nq) {
  if (q < nq) {
    f4 v = ((const f4*)s)[q];
    u16x4 o;
#pragma unroll
    for (int e = 0; e < 4; ++e) o[e] = f2bf(v[e]);
    ((u16x4*)d)[q] = o;
  }
}
// dt_w [768][24] f32 -> [768][32] bf16 zero-padded
DEV void cvt_pad(const float* __restrict__ s, u16* __restrict__ d, int q, int nq) {
  if (q < nq) {
    int e0 = q * 4, n = e0 >> 5, k = e0 & 31;
    u16x4 o;
#pragma unroll
    for (int e = 0; e < 4; ++e) {
      int kk = k + e;
      float v = (kk < 24) ? s[n * 24 + kk] : 0.f;
      o[e] = f2bf(v);
    }
    ((u16x4*)d)[q] = o;
  }
}

__global__ void k_cvtmulti(CvtArgs a) {
  int b = blockIdx.x;
  int i = 0;
#pragma unroll
  for (int j = 1; j < 9; ++j) i += (b >= a.bstart[j]);
#pragma unroll
  for (int j = 0; j < 9; ++j) {
    if (i == j) {
      int q = (b - a.bstart[j]) * 256 + threadIdx.x;
      if (j == 2 || j == 6) cvt_pad(a.src[j], a.dst[j], q, a.nq[j]);
      else                  cvt_plain(a.src[j], a.dst[j], q, a.nq[j]);
    }
  }
}

// ---------------- conv weight transpose [O][I][3] -> [I][3][O] ----------------
__global__ void k_wtrans(const float* __restrict__ in, float* __restrict__ out, int O, int I) {
  int n = O * I * 3;
  for (int g = blockIdx.x * blockDim.x + threadIdx.x; g < n; g += gridDim.x * blockDim.x) {
    int o = g / (I * 3);
    int rem = g - o * (I * 3);
    out[rem * O + o] = in[g];
  }
}

// ---------------- audio conv1: [2,80,1024] -> relu -> a1t [2,1024,192] ----------------
__global__ __launch_bounds__(192) void k_conv1(const float* __restrict__ audio,
    const float* __restrict__ w1t, const float* __restrict__ b1, float* __restrict__ a1t) {
  __shared__ float s[80][18];
  int bx = blockIdx.x;
  int b = bx >> 6, l0 = (bx & 63) << 4;
  int tid = threadIdx.x;
  for (int i = tid; i < 80 * 18; i += 192) {
    int ci = i / 18, dl = i - ci * 18;
    int l = l0 + dl - 1;
    s[ci][dl] = (l >= 0 && l < 1024) ? audio[(b * 80 + ci) * 1024 + l] : 0.f;
  }
  __syncthreads();
  int co = tid;
  float acc[16];
  float bias = b1[co];
#pragma unroll
  for (int i = 0; i < 16; ++i) acc[i] = bias;
  for (int ci = 0; ci < 80; ++ci) {
#pragma unroll
    for (int j = 0; j < 3; ++j) {
      float w = w1t[(ci * 3 + j) * 192 + co];
#pragma unroll
      for (int ls = 0; ls < 16; ++ls) acc[ls] = fmaf(s[ci][ls + j], w, acc[ls]);
    }
  }
#pragma unroll
  for (int ls = 0; ls < 16; ++ls) {
    float v = acc[ls] > 0.f ? acc[ls] : 0.f;
    a1t[(b * 1024 + l0 + ls) * 192 + co] = v;
  }
}

// ---------------- audio conv2: a1t -> bf16 X rows [b*2048 + l][384] ----------------
__global__ __launch_bounds__(384) void k_conv2b(const float* __restrict__ a1t,
    const float* __restrict__ w2t, const float* __restrict__ b2, u16* __restrict__ Xb) {
  __shared__ float s[10][192];
  int bx = blockIdx.x;
  int b = bx >> 7, l0 = (bx & 127) << 3;
  int tid = threadIdx.x;
  for (int i = tid; i < 10 * 192; i += 384) {
    int dl = i / 192, ci = i - dl * 192;
    int l = l0 + dl - 1;
    s[dl][ci] = (l >= 0 && l < 1024) ? a1t[(b * 1024 + l) * 192 + ci] : 0.f;
  }
  __syncthreads();
  int co = tid;
  float acc[8];
  float bias = b2[co];
#pragma unroll
  for (int i = 0; i < 8; ++i) acc[i] = bias;
  for (int ci = 0; ci < 192; ++ci) {
#pragma unroll
    for (int j = 0; j < 3; ++j) {
      float w = w2t[(ci * 3 + j) * 384 + co];
#pragma unroll
      for (int ls = 0; ls < 8; ++ls) acc[ls] = fmaf(s[ls + j][ci], w, acc[ls]);
    }
  }
#pragma unroll
  for (int ls = 0; ls < 8; ++ls)
    Xb[((size_t)(b * 2048 + l0 + ls)) * 384 + co] = f2bf(acc[ls]);
}

// ---------------- text embedding gather -> bf16 X rows [b*2048+1024+t] ----------------
__global__ void k_embedb(const int* __restrict__ tok, const float* __restrict__ emb,
                         u16* __restrict__ Xb) {
  int gid = blockIdx.x * blockDim.x + threadIdx.x;
  if (gid >= 2 * 1024 * 96) return;
  int q = gid % 96;
  int rt = gid / 96;
  int b = rt >> 10, t = rt & 1023;
  int tk = tok[b * 1024 + t];
  f4 v = *(const f4*)(emb + (size_t)tk * 384 + q * 4);
  u16x4 o;
#pragma unroll
  for (int e = 0; e < 4; ++e) o[e] = f2bf(v[e]);
  *(u16x4*)(Xb + ((size_t)(b * 2048 + 1024 + t)) * 384 + q * 4) = o;
}

// ---------------- depthwise causal conv (K=4) + silu: dual f32+bf16 output ----------------
__global__ void k_dwconv2(const float* __restrict__ xz, const float* __restrict__ cw,
                          const float* __restrict__ cb, float* __restrict__ xif,
                          u16* __restrict__ xib) {
  int gid = blockIdx.x * blockDim.x + threadIdx.x;
  if (gid >= 4096 * 192) return;
  int d4 = gid % 192;
  int row = gid / 192;
  int b = row >> 11, l = row & 2047;
  int d = d4 * 4;
  f4 cw0 = *(const f4*)(cw + d * 4);
  f4 cw1 = *(const f4*)(cw + d * 4 + 4);
  f4 cw2 = *(const f4*)(cw + d * 4 + 8);
  f4 cw3 = *(const f4*)(cw + d * 4 + 12);
  f4 acc = *(const f4*)(cb + d);
#pragma unroll
  for (int j = 0; j < 4; ++j) {
    int lj = l - 3 + j;
    if (lj >= 0) {
      f4 v = *(const f4*)(xz + ((size_t)(b * 2048 + lj)) * 1536 + d);
      acc[0] = fmaf(v[0], cw0[j], acc[0]);
      acc[1] = fmaf(v[1], cw1[j], acc[1]);
      acc[2] = fmaf(v[2], cw2[j], acc[2]);
      acc[3] = fmaf(v[3], cw3[j], acc[3]);
    }
  }
  f4 o;
  u16x4 ob;
#pragma unroll
  for (int e = 0; e < 4; ++e) { o[e] = siluf(acc[e]); ob[e] = f2bf(o[e]); }
  *(f4*)(xif + (size_t)row * 768 + d) = o;
  *(u16x4*)(xib + (size_t)row * 768 + d) = ob;
}

// ---------------- bf16 MFMA GEMM, 2-phase double-buffered LDS (r3 known-good) ----------------
// C[m,n] = act(sum_k A[m,k]*W[n,k] + bias[n]); M mult of TILE, K mult of 32.
// TILE: 128 (4 waves x 64x64) or 64 (4 waves x 32x32). OUTB: 0=f32,1=bf16,2=both.
template <int TILE, int BIAS, int ACT, int OUTB, int SWZ>
__global__ __launch_bounds__(256) void k_gemm2(
    const u16* __restrict__ A, int lda, const u16* __restrict__ W, int ldw,
    const float* __restrict__ bias, float* __restrict__ C, u16* __restrict__ Cb,
    int ldc, int M, int N, int K) {
  constexpr int MF = (TILE == 128) ? 4 : 2;
  constexpr int TB = TILE * 32;
  __shared__ u16 As[2][TB], Ws[2][TB];
  int bid = blockIdx.x;
  if (SWZ) {
    int nwg = gridDim.x;
    int q = nwg >> 3, r = nwg & 7;
    int xcd = bid & 7, li = bid >> 3;
    bid = (xcd < r ? xcd * (q + 1) : r * (q + 1) + (xcd - r) * q) + li;
  }
  int bm, bn;
  if (TILE == 128) { bm = (bid & 31) << 7; bn = (bid >> 5) << 7; }
  else             { bm = (bid & 63) << 6; bn = (bid >> 6) << 6; }
  int t = threadIdx.x, lane = t & 63, wave = t >> 6;
  int wm0, wn0;
  if (TILE == 128) { wm0 = (wave >> 1) << 6; wn0 = (wave & 1) << 6; }
  else             { wm0 = (wave >> 1) << 5; wn0 = (wave & 1) << 5; }
  int fr = lane & 15, fk = (lane >> 4) << 3;
  int r0 = t >> 2, sl = (t & 3) << 3;
  const u16* gA0 = A + (size_t)(bm + r0) * lda + sl;
  const u16* gA1 = gA0 + (size_t)64 * lda;
  int n0 = bn + r0;      if (n0 > N - 1) n0 = N - 1;
  int n1 = bn + r0 + 64; if (n1 > N - 1) n1 = N - 1;
  const u16* gW0 = W + (size_t)n0 * ldw + sl;
  const u16* gW1 = W + (size_t)n1 * ldw + sl;
  f32x4 acc[MF][MF] = {};
  int nk = K >> 5;
  auto stage = [&](int buf, int k0) {
    gload16(gA0 + k0, As[buf] + t * 8);
    gload16(gW0 + k0, Ws[buf] + t * 8);
    if (TILE == 128) {
      gload16(gA1 + k0, As[buf] + t * 8 + 2048);
      gload16(gW1 + k0, Ws[buf] + t * 8 + 2048);
    }
  };
  stage(0, 0);
  __syncthreads();
  for (int s = 0; s < nk; ++s) {
    int cur = s & 1;
    short8 af[MF], wf[MF];
#pragma unroll
    for (int mi = 0; mi < MF; ++mi) af[mi] = *(const short8*)&As[cur][(wm0 + mi * 16 + fr) * 32 + fk];
#pragma unroll
    for (int ni = 0; ni < MF; ++ni) wf[ni] = *(const short8*)&Ws[cur][(wn0 + ni * 16 + fr) * 32 + fk];
    if (s + 1 < nk) stage(cur ^ 1, (s + 1) << 5);
#pragma unroll
    for (int mi = 0; mi < MF; ++mi)
#pragma unroll
      for (int ni = 0; ni < MF; ++ni)
        acc[mi][ni] = __builtin_amdgcn_mfma_f32_16x16x32_bf16(af[mi], wf[ni], acc[mi][ni], 0, 0, 0);
    __syncthreads();
  }
  int frow = (lane >> 4) << 2;
#pragma unroll
  for (int ni = 0; ni < MF; ++ni) {
    int col = bn + wn0 + ni * 16 + fr;
    if (col < N) {
      float bv = BIAS ? bias[col] : 0.f;
#pragma unroll
      for (int mi = 0; mi < MF; ++mi) {
        int row = bm + wm0 + mi * 16 + frow;
#pragma unroll
        for (int rr = 0; rr < 4; ++rr) {
          float v = acc[mi][ni][rr] + bv;
          if (ACT == 1) v = (v > 20.f) ? v : log1pf(__expf(v));
          size_t o = (size_t)(row + rr) * ldc + col;
          if (OUTB == 0) C[o] = v;
          else if (OUTB == 1) Cb[o] = f2bf(v);
          else { C[o] = v; Cb[o] = f2bf(v); }
        }
      }
    }
  }
}

// ---------------- final GEMM: BM=64 x BN=256 (halves partial-line write boundaries) ----------
// 4 waves (2M x 2N), per-wave 32x128. 2-phase dbuf, XCD-swizzled, f32 out + bias.
__global__ __launch_bounds__(256, 3) void k_gemmF(
    const u16* __restrict__ A, int lda, const u16* __restrict__ W, int ldw,
    const float* __restrict__ bias, float* __restrict__ C,
    int ldc, int M, int N, int K) {
  __shared__ u16 As[2][64 * 32], Ws[2][256 * 32];
  int bid = blockIdx.x;
  {
    int nwg = gridDim.x;
    int q = nwg >> 3, r = nwg & 7;
    int xcd = bid & 7, li = bid >> 3;
    bid = (xcd < r ? xcd * (q + 1) : r * (q + 1) + (xcd - r) * q) + li;
  }
  int bm = (bid & 63) << 6;          // M=4096 -> 64 m-blocks; consecutive bids share W-panel
  int bn = (bid >> 6) << 8;
  int t = threadIdx.x, lane = t & 63, wave = t >> 6;
  int wm0 = (wave >> 1) << 5;        // 0 / 32
  int wn0 = (wave & 1) << 7;         // 0 / 128
  int fr = lane & 15, fk = (lane >> 4) << 3;
  int rA = t >> 2, sl = (t & 3) << 3;
  const u16* gA = A + (size_t)(bm + rA) * lda + sl;
  const u16* gW[4];
#pragma unroll
  for (int i = 0; i < 4; ++i) {
    int gn = bn + rA + i * 64;
    if (gn > N - 1) gn = N - 1;
    gW[i] = W + (size_t)gn * ldw + sl;
  }
  f32x4 acc[2][8] = {};
  int nk = K >> 5;
  auto stage = [&](int buf, int k0) {
    gload16(gA + k0, As[buf] + t * 8);
#pragma unroll
    for (int i = 0; i < 4; ++i)
      gload16(gW[i] + k0, Ws[buf] + t * 8 + i * 2048);
  };
  stage(0, 0);
  __syncthreads();
  for (int s = 0; s < nk; ++s) {
    int cur = s & 1;
    short8 af[2], wf[8];
#pragma unroll
    for (int mi = 0; mi < 2; ++mi) af[mi] = *(const short8*)&As[cur][(wm0 + mi * 16 + fr) * 32 + fk];
#pragma unroll
    for (int ni = 0; ni < 8; ++ni) wf[ni] = *(const short8*)&Ws[cur][(wn0 + ni * 16 + fr) * 32 + fk];
    if (s + 1 < nk) stage(cur ^ 1, (s + 1) << 5);
#pragma unroll
    for (int mi = 0; mi < 2; ++mi)
#pragma unroll
      for (int ni = 0; ni < 8; ++ni)
        acc[mi][ni] = __builtin_amdgcn_mfma_f32_16x16x32_bf16(af[mi], wf[ni], acc[mi][ni], 0, 0, 0);
    __syncthreads();
  }
  int frow = (lane >> 4) << 2;
#pragma unroll
  for (int ni = 0; ni < 8; ++ni) {
    int col = bn + wn0 + ni * 16 + fr;
    if (col < N) {
      float bv = bias[col];
#pragma unroll
      for (int mi = 0; mi < 2; ++mi) {
        int row = bm + wm0 + mi * 16 + frow;
#pragma unroll
        for (int rr = 0; rr < 4; ++rr)
          C[(size_t)(row + rr) * ldc + col] = acc[mi][ni][rr] + bv;
      }
    }
  }
}

// ---------------- segmented selective scan ----------------
__global__ __launch_bounds__(64) void k_scanA(
    const float* __restrict__ dt, const float* __restrict__ xdbl,
    const float* __restrict__ xi, const float* __restrict__ A_log,
    float* __restrict__ Hloc, float* __restrict__ Sdt) {
  int b = blockIdx.y, seg = blockIdx.z;
  int ch0 = blockIdx.x * 4;
  int tid = threadIdx.x;
  int c = tid >> 4, n = tid & 15;
  int d = ch0 + c;
  float a = -__expf(A_log[d * 16 + n]);
  float h = 0.f, sdt = 0.f;
  size_t row = (size_t)b * 2048 + seg * 64;
#pragma unroll 4
  for (int i = 0; i < 64; ++i, ++row) {
    float dtv = dt[row * 768 + d];
    float xiv = xi[row * 768 + d];
    float Bv = xdbl[row * 56 + 24 + n];
    float da = __expf(dtv * a);
    h = fmaf(da, h, dtv * Bv * xiv);
    sdt += dtv;
  }
  size_t o = (((size_t)b * 32 + seg) * 768 + d) * 16 + n;
  Hloc[o] = h;
  if (n == 0) Sdt[((size_t)b * 32 + seg) * 768 + d] = sdt;
}

__global__ __launch_bounds__(256) void k_scanB(
    const float* __restrict__ Hloc, const float* __restrict__ Sdt,
    const float* __restrict__ A_log, float* __restrict__ Hini) {
  int gid = blockIdx.x * 256 + threadIdx.x;
  if (gid >= 24576) return;
  int b = gid / 12288;
  int r = gid - b * 12288;
  int d = r >> 4, n = r & 15;
  float a = -__expf(A_log[d * 16 + n]);
  float h = 0.f;
  for (int s = 0; s < 32; ++s) {
    size_t o = (((size_t)b * 32 + s) * 768 + d) * 16 + n;
    Hini[o] = h;
    float P = __expf(a * Sdt[((size_t)b * 32 + s) * 768 + d]);
    h = fmaf(P, h, Hloc[o]);
  }
}

__global__ __launch_bounds__(64) void k_scanC(
    const float* __restrict__ dt, const float* __restrict__ xdbl,
    const float* __restrict__ xi, const float* __restrict__ xz,
    const float* __restrict__ A_log, const float* __restrict__ Dp,
    const float* __restrict__ Hini, u16* __restrict__ y) {
  __shared__ float s_y[64][4];
  int b = blockIdx.y, seg = blockIdx.z;
  int ch0 = blockIdx.x * 4;
  int tid = threadIdx.x;
  int c = tid >> 4, n = tid & 15;
  int d = ch0 + c;
  float a = -__expf(A_log[d * 16 + n]);
  float h = Hini[(((size_t)b * 32 + seg) * 768 + d) * 16 + n];
  size_t row = (size_t)b * 2048 + seg * 64;
#pragma unroll 2
  for (int i = 0; i < 64; ++i, ++row) {
    float dtv = dt[row * 768 + d];
    float xiv = xi[row * 768 + d];
    float Bv = xdbl[row * 56 + 24 + n];
    float Cv = xdbl[row * 56 + 40 + n];
    float da = __expf(dtv * a);
    h = fmaf(da, h, dtv * Bv * xiv);
    float yv = h * Cv;
    yv += __shfl_xor(yv, 1);
    yv += __shfl_xor(yv, 2);
    yv += __shfl_xor(yv, 4);
    yv += __shfl_xor(yv, 8);
    if (n == 0) s_y[i][c] = yv;
  }
  __syncthreads();
  size_t rw = (size_t)b * 2048 + seg * 64 + tid;
  f4 xiv4 = *(const f4*)(xi + rw * 768 + ch0);
  f4 dpv = *(const f4*)(Dp + ch0);
  f4 zv = *(const f4*)(xz + rw * 1536 + 768 + ch0);
  u16x4 ob;
#pragma unroll
  for (int e = 0; e < 4; ++e) {
    float o = (s_y[tid][e] + xiv4[e] * dpv[e]) * siluf(zv[e]);
    ob[e] = f2bf(o);
  }
  *(u16x4*)(y + rw * 768 + ch0) = ob;
}

// =====================================================================================
extern "C" void kernel_launch(void* const* d_in, const int* in_sizes, int n_in,
                              void* d_out, int out_size, void* d_ws, size_t ws_size,
                              hipStream_t stream) {
  const float* audio   = (const float*)d_in[0];
  const int*   tokens  = (const int*)d_in[1];
  const float* conv1_w = (const float*)d_in[2];
  const float* conv1_b = (const float*)d_in[3];
  const float* conv2_w = (const float*)d_in[4];
  const float* conv2_b = (const float*)d_in[5];
  const float* embedw  = (const float*)d_in[6];
  const float* P1[9], *P2[9];
  for (int i = 0; i < 9; ++i) { P1[i] = (const float*)d_in[7 + i]; P2[i] = (const float*)d_in[16 + i]; }
  const float* proj_w = (const float*)d_in[25];
  const float* proj_b = (const float*)d_in[26];
  (void)in_sizes; (void)n_in; (void)out_size; (void)ws_size;

  // ---- arena in d_out (fully overwritten by final GEMM) ----
  float* base = (float*)d_out;
  size_t off = 0;
  auto af = [&](size_t n) { float* p = base + off; off += n; return p; };
  float* xz   = af((size_t)4096 * 1536);
  float* xif  = af((size_t)4096 * 768);
  float* xdbl = af((size_t)4096 * 56);
  float* dtb  = af((size_t)4096 * 768);
  float* a1t  = af((size_t)2 * 1024 * 192);
  float* w1t  = af((size_t)80 * 3 * 192);
  float* w2t  = af((size_t)192 * 3 * 384);
  float* Hloc = af((size_t)2 * 32 * 768 * 16);
  float* Hini = af((size_t)2 * 32 * 768 * 16);
  float* Sdt  = af((size_t)2 * 32 * 768);
  u16* ub = (u16*)(base + off);
  size_t uoff = 0;
  auto au = [&](size_t n) { u16* p = ub + uoff; uoff += n; return p; };
  u16* Xin_b  = au((size_t)4096 * 384);
  u16* Xmid_b = au((size_t)4096 * 384);
  u16* xib    = au((size_t)4096 * 768);
  u16* xdblb  = au((size_t)4096 * 56);
  u16* yb16   = au((size_t)4096 * 768);
  u16* Wi1 = au((size_t)1536 * 384);
  u16* Wx1 = au((size_t)56 * 768);
  u16* Wd1 = au((size_t)768 * 32);
  u16* Wo1 = au((size_t)384 * 768);
  u16* Wi2 = au((size_t)1536 * 384);
  u16* Wx2 = au((size_t)56 * 768);
  u16* Wd2 = au((size_t)768 * 32);
  u16* Wo2 = au((size_t)384 * 768);
  u16* X2b    = (u16*)d_ws;                       // survive final GEMM's d_out writes
  u16* projwb = X2b + (size_t)4096 * 384;

  // ---- one batched weight-convert kernel ----
  CvtArgs ca;
  const float* srcs[9] = {P1[0], P1[3], P1[4], P1[8], P2[0], P2[3], P2[4], P2[8], proj_w};
  u16* dsts[9] = {Wi1, Wx1, Wd1, Wo1, Wi2, Wx2, Wd2, Wo2, projwb};
  int nqs[9] = {147456, 10752, 6144, 73728, 147456, 10752, 6144, 73728, 4824672};
  int cum = 0;
  for (int j = 0; j < 9; ++j) {
    ca.src[j] = srcs[j]; ca.dst[j] = dsts[j]; ca.nq[j] = nqs[j];
    ca.bstart[j] = cum; cum += (nqs[j] + 255) / 256;
  }
  ca.bstart[9] = cum;
  k_cvtmulti<<<dim3(cum), dim3(256), 0, stream>>>(ca);

  // ---- audio frontend + embedding -> Xin_b bf16 ----
  k_wtrans<<<dim3(180), dim3(256), 0, stream>>>(conv1_w, w1t, 192, 80);
  k_wtrans<<<dim3(864), dim3(256), 0, stream>>>(conv2_w, w2t, 384, 192);
  k_conv1<<<dim3(128), dim3(192), 0, stream>>>(audio, w1t, conv1_b, a1t);
  k_conv2b<<<dim3(256), dim3(384), 0, stream>>>(a1t, w2t, conv2_b, Xin_b);
  k_embedb<<<dim3(768), dim3(256), 0, stream>>>(tokens, embedw, Xin_b);

  auto run_mamba = [&](const float* const* P, const u16* Xin, u16* Xout,
                       const u16* Wi, const u16* Wx, const u16* Wd, const u16* Wo) {
    k_gemm2<128, 0, 0, 0, 0><<<dim3(32 * 12), dim3(256), 0, stream>>>(
        Xin, 384, Wi, 384, nullptr, xz, nullptr, 1536, 4096, 1536, 384);
    k_dwconv2<<<dim3(3072), dim3(256), 0, stream>>>(xz, P[1], P[2], xif, xib);
    k_gemm2<64, 0, 0, 2, 0><<<dim3(64 * 1), dim3(256), 0, stream>>>(
        xib, 768, Wx, 768, nullptr, xdbl, xdblb, 56, 4096, 56, 768);
    k_gemm2<64, 1, 1, 0, 0><<<dim3(64 * 12), dim3(256), 0, stream>>>(
        xdblb, 56, Wd, 32, P[5], dtb, nullptr, 768, 4096, 768, 32);
    k_scanA<<<dim3(192, 2, 32), dim3(64), 0, stream>>>(dtb, xdbl, xif, P[6], Hloc, Sdt);
    k_scanB<<<dim3(96), dim3(256), 0, stream>>>(Hloc, Sdt, P[6], Hini);
    k_scanC<<<dim3(192, 2, 32), dim3(64), 0, stream>>>(dtb, xdbl, xif, xz, P[6], P[7], Hini, yb16);
    k_gemm2<64, 0, 0, 1, 0><<<dim3(64 * 6), dim3(256), 0, stream>>>(
        yb16, 768, Wo, 768, nullptr, nullptr, Xout, 384, 4096, 384, 768);
  };
  run_mamba(P1, Xin_b, Xmid_b, Wi1, Wx1, Wd1, Wo1);
  run_mamba(P2, Xmid_b, X2b, Wi2, Wx2, Wd2, Wo2);

  // ---- final projection -> d_out [4096, 50257] f32 (BM64 x BN256, XCD-swizzled) ----
  k_gemmF<<<dim3(64 * 197), dim3(256), 0, stream>>>(
      X2b, 384, projwb, 384, proj_b, (float*)d_out, 50257, 4096, 50257, 384);
}

// Round 6
// 886.394 us; speedup vs baseline: 1.1242x; 1.0146x over previous
//
#include <hip/hip_runtime.h>

typedef unsigned short u16;
typedef __attribute__((ext_vector_type(4))) float f4;
typedef __attribute__((ext_vector_type(4))) float f32x4;
typedef __attribute__((ext_vector_type(8))) short short8;
typedef __attribute__((ext_vector_type(4))) unsigned short u16x4;

#define DEV static __device__ __forceinline__

DEV u16 f2bf(float f) {                    // round-to-nearest-even f32->bf16
  unsigned u = __float_as_uint(f);
  u += 0x7fffu + ((u >> 16) & 1u);
  return (u16)(u >> 16);
}
DEV float siluf(float z) { return z / (1.f + __expf(-z)); }

// async global->LDS, 16B per lane (wave-uniform LDS base + lane*16)
DEV void gload16(const u16* g, const u16* l) {
  __builtin_amdgcn_global_load_lds(
      (const __attribute__((address_space(1))) unsigned int*)(unsigned long long)g,
      (__attribute__((address_space(3))) unsigned int*)(unsigned int)(unsigned long long)l,
      16, 0, 0);
}

// ---------------- batched weight converts (8 mamba weights + proj_w) ----------------
struct CvtArgs {
  const float* src[9];
  u16* dst[9];
  int bstart[10];
  int nq[9];
};

DEV void cvt_plain(const float* __restrict__ s, u16* __restrict__ d, int q, int nq) {
  if (q < nq) {
    f4 v = ((const f4*)s)[q];
    u16x4 o;
#pragma unroll
    for (int e = 0; e < 4; ++e) o[e] = f2bf(v[e]);
    ((u16x4*)d)[q] = o;
  }
}
// dt_w [768][24] f32 -> [768][32] bf16 zero-padded
DEV void cvt_pad(const float* __restrict__ s, u16* __restrict__ d, int q, int nq) {
  if (q < nq) {
    int e0 = q * 4, n = e0 >> 5, k = e0 & 31;
    u16x4 o;
#pragma unroll
    for (int e = 0; e < 4; ++e) {
      int kk = k + e;
      float v = (kk < 24) ? s[n * 24 + kk] : 0.f;
      o[e] = f2bf(v);
    }
    ((u16x4*)d)[q] = o;
  }
}

__global__ void k_cvtmulti(CvtArgs a) {
  int b = blockIdx.x;
  int i = 0;
#pragma unroll
  for (int j = 1; j < 9; ++j) i += (b >= a.bstart[j]);
#pragma unroll
  for (int j = 0; j < 9; ++j) {
    if (i == j) {
      int q = (b - a.bstart[j]) * 256 + threadIdx.x;
      if (j == 2 || j == 6) cvt_pad(a.src[j], a.dst[j], q, a.nq[j]);
      else                  cvt_plain(a.src[j], a.dst[j], q, a.nq[j]);
    }
  }
}

// ---------------- conv weight transpose [O][I][3] -> [I][3][O] ----------------
__global__ void k_wtrans(const float* __restrict__ in, float* __restrict__ out, int O, int I) {
  int n = O * I * 3;
  for (int g = blockIdx.x * blockDim.x + threadIdx.x; g < n; g += gridDim.x * blockDim.x) {
    int o = g / (I * 3);
    int rem = g - o * (I * 3);
    out[rem * O + o] = in[g];
  }
}

// ---------------- audio conv1: [2,80,1024] -> relu -> a1t [2,1024,192] ----------------
__global__ __launch_bounds__(192) void k_conv1(const float* __restrict__ audio,
    const float* __restrict__ w1t, const float* __restrict__ b1, float* __restrict__ a1t) {
  __shared__ float s[80][18];
  int bx = blockIdx.x;
  int b = bx >> 6, l0 = (bx & 63) << 4;
  int tid = threadIdx.x;
  for (int i = tid; i < 80 * 18; i += 192) {
    int ci = i / 18, dl = i - ci * 18;
    int l = l0 + dl - 1;
    s[ci][dl] = (l >= 0 && l < 1024) ? audio[(b * 80 + ci) * 1024 + l] : 0.f;
  }
  __syncthreads();
  int co = tid;
  float acc[16];
  float bias = b1[co];
#pragma unroll
  for (int i = 0; i < 16; ++i) acc[i] = bias;
  for (int ci = 0; ci < 80; ++ci) {
#pragma unroll
    for (int j = 0; j < 3; ++j) {
      float w = w1t[(ci * 3 + j) * 192 + co];
#pragma unroll
      for (int ls = 0; ls < 16; ++ls) acc[ls] = fmaf(s[ci][ls + j], w, acc[ls]);
    }
  }
#pragma unroll
  for (int ls = 0; ls < 16; ++ls) {
    float v = acc[ls] > 0.f ? acc[ls] : 0.f;
    a1t[(b * 1024 + l0 + ls) * 192 + co] = v;
  }
}

// ---------------- audio conv2: a1t -> bf16 X rows [b*2048 + l][384] ----------------
__global__ __launch_bounds__(384) void k_conv2b(const float* __restrict__ a1t,
    const float* __restrict__ w2t, const float* __restrict__ b2, u16* __restrict__ Xb) {
  __shared__ float s[10][192];
  int bx = blockIdx.x;
  int b = bx >> 7, l0 = (bx & 127) << 3;
  int tid = threadIdx.x;
  for (int i = tid; i < 10 * 192; i += 384) {
    int dl = i / 192, ci = i - dl * 192;
    int l = l0 + dl - 1;
    s[dl][ci] = (l >= 0 && l < 1024) ? a1t[(b * 1024 + l) * 192 + ci] : 0.f;
  }
  __syncthreads();
  int co = tid;
  float acc[8];
  float bias = b2[co];
#pragma unroll
  for (int i = 0; i < 8; ++i) acc[i] = bias;
  for (int ci = 0; ci < 192; ++ci) {
#pragma unroll
    for (int j = 0; j < 3; ++j) {
      float w = w2t[(ci * 3 + j) * 384 + co];
#pragma unroll
      for (int ls = 0; ls < 8; ++ls) acc[ls] = fmaf(s[ls + j][ci], w, acc[ls]);
    }
  }
#pragma unroll
  for (int ls = 0; ls < 8; ++ls)
    Xb[((size_t)(b * 2048 + l0 + ls)) * 384 + co] = f2bf(acc[ls]);
}

// ---------------- text embedding gather -> bf16 X rows [b*2048+1024+t] ----------------
__global__ void k_embedb(const int* __restrict__ tok, const float* __restrict__ emb,
                         u16* __restrict__ Xb) {
  int gid = blockIdx.x * blockDim.x + threadIdx.x;
  if (gid >= 2 * 1024 * 96) return;
  int q = gid % 96;
  int rt = gid / 96;
  int b = rt >> 10, t = rt & 1023;
  int tk = tok[b * 1024 + t];
  f4 v = *(const f4*)(emb + (size_t)tk * 384 + q * 4);
  u16x4 o;
#pragma unroll
  for (int e = 0; e < 4; ++e) o[e] = f2bf(v[e]);
  *(u16x4*)(Xb + ((size_t)(b * 2048 + 1024 + t)) * 384 + q * 4) = o;
}

// ---------------- depthwise causal conv (K=4) + silu: dual f32+bf16 output ----------------
__global__ void k_dwconv2(const float* __restrict__ xz, const float* __restrict__ cw,
                          const float* __restrict__ cb, float* __restrict__ xif,
                          u16* __restrict__ xib) {
  int gid = blockIdx.x * blockDim.x + threadIdx.x;
  if (gid >= 4096 * 192) return;
  int d4 = gid % 192;
  int row = gid / 192;
  int b = row >> 11, l = row & 2047;
  int d = d4 * 4;
  f4 cw0 = *(const f4*)(cw + d * 4);
  f4 cw1 = *(const f4*)(cw + d * 4 + 4);
  f4 cw2 = *(const f4*)(cw + d * 4 + 8);
  f4 cw3 = *(const f4*)(cw + d * 4 + 12);
  f4 acc = *(const f4*)(cb + d);
#pragma unroll
  for (int j = 0; j < 4; ++j) {
    int lj = l - 3 + j;
    if (lj >= 0) {
      f4 v = *(const f4*)(xz + ((size_t)(b * 2048 + lj)) * 1536 + d);
      acc[0] = fmaf(v[0], cw0[j], acc[0]);
      acc[1] = fmaf(v[1], cw1[j], acc[1]);
      acc[2] = fmaf(v[2], cw2[j], acc[2]);
      acc[3] = fmaf(v[3], cw3[j], acc[3]);
    }
  }
  f4 o;
  u16x4 ob;
#pragma unroll
  for (int e = 0; e < 4; ++e) { o[e] = siluf(acc[e]); ob[e] = f2bf(o[e]); }
  *(f4*)(xif + (size_t)row * 768 + d) = o;
  *(u16x4*)(xib + (size_t)row * 768 + d) = ob;
}

// ---------------- bf16 MFMA GEMM, 2-phase double-buffered LDS (known-good) ----------------
// C[m,n] = act(sum_k A[m,k]*W[n,k] + bias[n]); M mult of TILE, K mult of 32.
// TILE: 128 (4 waves x 64x64) or 64 (4 waves x 32x32). OUTB: 0=f32,1=bf16,2=both.
template <int TILE, int BIAS, int ACT, int OUTB, int SWZ>
__global__ __launch_bounds__(256) void k_gemm2(
    const u16* __restrict__ A, int lda, const u16* __restrict__ W, int ldw,
    const float* __restrict__ bias, float* __restrict__ C, u16* __restrict__ Cb,
    int ldc, int M, int N, int K) {
  constexpr int MF = (TILE == 128) ? 4 : 2;
  constexpr int TB = TILE * 32;
  __shared__ u16 As[2][TB], Ws[2][TB];
  int bid = blockIdx.x;
  if (SWZ) {
    int nwg = gridDim.x;
    int q = nwg >> 3, r = nwg & 7;
    int xcd = bid & 7, li = bid >> 3;
    bid = (xcd < r ? xcd * (q + 1) : r * (q + 1) + (xcd - r) * q) + li;
  }
  int bm, bn;
  if (TILE == 128) { bm = (bid & 31) << 7; bn = (bid >> 5) << 7; }
  else             { bm = (bid & 63) << 6; bn = (bid >> 6) << 6; }
  int t = threadIdx.x, lane = t & 63, wave = t >> 6;
  int wm0, wn0;
  if (TILE == 128) { wm0 = (wave >> 1) << 6; wn0 = (wave & 1) << 6; }
  else             { wm0 = (wave >> 1) << 5; wn0 = (wave & 1) << 5; }
  int fr = lane & 15, fk = (lane >> 4) << 3;
  int r0 = t >> 2, sl = (t & 3) << 3;
  const u16* gA0 = A + (size_t)(bm + r0) * lda + sl;
  const u16* gA1 = gA0 + (size_t)64 * lda;
  int n0 = bn + r0;      if (n0 > N - 1) n0 = N - 1;
  int n1 = bn + r0 + 64; if (n1 > N - 1) n1 = N - 1;
  const u16* gW0 = W + (size_t)n0 * ldw + sl;
  const u16* gW1 = W + (size_t)n1 * ldw + sl;
  f32x4 acc[MF][MF] = {};
  int nk = K >> 5;
  auto stage = [&](int buf, int k0) {
    gload16(gA0 + k0, As[buf] + t * 8);
    gload16(gW0 + k0, Ws[buf] + t * 8);
    if (TILE == 128) {
      gload16(gA1 + k0, As[buf] + t * 8 + 2048);
      gload16(gW1 + k0, Ws[buf] + t * 8 + 2048);
    }
  };
  stage(0, 0);
  __syncthreads();
  for (int s = 0; s < nk; ++s) {
    int cur = s & 1;
    short8 af[MF], wf[MF];
#pragma unroll
    for (int mi = 0; mi < MF; ++mi) af[mi] = *(const short8*)&As[cur][(wm0 + mi * 16 + fr) * 32 + fk];
#pragma unroll
    for (int ni = 0; ni < MF; ++ni) wf[ni] = *(const short8*)&Ws[cur][(wn0 + ni * 16 + fr) * 32 + fk];
    if (s + 1 < nk) stage(cur ^ 1, (s + 1) << 5);
#pragma unroll
    for (int mi = 0; mi < MF; ++mi)
#pragma unroll
      for (int ni = 0; ni < MF; ++ni)
        acc[mi][ni] = __builtin_amdgcn_mfma_f32_16x16x32_bf16(af[mi], wf[ni], acc[mi][ni], 0, 0, 0);
    __syncthreads();
  }
  int frow = (lane >> 4) << 2;
#pragma unroll
  for (int ni = 0; ni < MF; ++ni) {
    int col = bn + wn0 + ni * 16 + fr;
    if (col < N) {
      float bv = BIAS ? bias[col] : 0.f;
#pragma unroll
      for (int mi = 0; mi < MF; ++mi) {
        int row = bm + wm0 + mi * 16 + frow;
#pragma unroll
        for (int rr = 0; rr < 4; ++rr) {
          float v = acc[mi][ni][rr] + bv;
          if (ACT == 1) v = (v > 20.f) ? v : log1pf(__expf(v));
          size_t o = (size_t)(row + rr) * ldc + col;
          if (OUTB == 0) C[o] = v;
          else if (OUTB == 1) Cb[o] = f2bf(v);
          else { C[o] = v; Cb[o] = f2bf(v); }
        }
      }
    }
  }
}

// ---------------- final GEMM: BM=64 x BN=256, 4 blocks/CU, row-burst stores ----------
// 4 waves (2M x 2N), per-wave 32x128. 2-phase dbuf, XCD-swizzled, f32 out + bias.
__global__ __launch_bounds__(256, 4) void k_gemmF(
    const u16* __restrict__ A, int lda, const u16* __restrict__ W, int ldw,
    const float* __restrict__ bias, float* __restrict__ C,
    int ldc, int M, int N, int K) {
  __shared__ u16 As[2][64 * 32], Ws[2][256 * 32];   // 40 KB -> 4 blocks/CU
  int bid = blockIdx.x;
  {
    int nwg = gridDim.x;
    int q = nwg >> 3, r = nwg & 7;
    int xcd = bid & 7, li = bid >> 3;
    bid = (xcd < r ? xcd * (q + 1) : r * (q + 1) + (xcd - r) * q) + li;
  }
  int bm = (bid & 63) << 6;          // m-minor: consecutive bids share W-panel
  int bn = (bid >> 6) << 8;
  int t = threadIdx.x, lane = t & 63, wave = t >> 6;
  int wm0 = (wave >> 1) << 5;        // 0 / 32
  int wn0 = (wave & 1) << 7;         // 0 / 128
  int fr = lane & 15, fk = (lane >> 4) << 3;
  int rA = t >> 2, sl = (t & 3) << 3;
  const u16* gA = A + (size_t)(bm + rA) * lda + sl;
  int nrow[4];
#pragma unroll
  for (int i = 0; i < 4; ++i) {
    int gn = bn + rA + i * 64;
    nrow[i] = (gn > N - 1) ? (N - 1) : gn;
  }
  const u16* gWs = W + sl;
  f32x4 acc[2][8] = {};
  int nk = K >> 5;
  auto stage = [&](int buf, int k0) {
    gload16(gA + k0, As[buf] + t * 8);
#pragma unroll
    for (int i = 0; i < 4; ++i)
      gload16(gWs + (size_t)nrow[i] * ldw + k0, Ws[buf] + t * 8 + i * 2048);
  };
  stage(0, 0);
  __syncthreads();
  for (int s = 0; s < nk; ++s) {
    int cur = s & 1;
    short8 af[2];
#pragma unroll
    for (int mi = 0; mi < 2; ++mi) af[mi] = *(const short8*)&As[cur][(wm0 + mi * 16 + fr) * 32 + fk];
    if (s + 1 < nk) stage(cur ^ 1, (s + 1) << 5);
#pragma unroll
    for (int ni = 0; ni < 8; ++ni) {
      short8 wf = *(const short8*)&Ws[cur][(wn0 + ni * 16 + fr) * 32 + fk];
#pragma unroll
      for (int mi = 0; mi < 2; ++mi)
        acc[mi][ni] = __builtin_amdgcn_mfma_f32_16x16x32_bf16(af[mi], wf, acc[mi][ni], 0, 0, 0);
    }
    __syncthreads();
  }
  int frow = (lane >> 4) << 2;
  float bv[8];
#pragma unroll
  for (int ni = 0; ni < 8; ++ni) {
    int col = bn + wn0 + ni * 16 + fr;
    bv[ni] = (col < N) ? bias[col] : 0.f;
  }
#pragma unroll
  for (int mi = 0; mi < 2; ++mi) {
#pragma unroll
    for (int rr = 0; rr < 4; ++rr) {
      int row = bm + wm0 + mi * 16 + frow + rr;
      float* Crow = C + (size_t)row * ldc;
#pragma unroll
      for (int ni = 0; ni < 8; ++ni) {
        int col = bn + wn0 + ni * 16 + fr;
        if (col < N) Crow[col] = acc[mi][ni][rr] + bv[ni];
      }
    }
  }
}

// ---------------- segmented selective scan ----------------
// XCD-affinity remap: blockIdx.x -> ch0 so that each XCD owns a contiguous
// 96-channel band; 128B lines of y/dt/xi are then shared by same-L2 blocks.
DEV int scan_ch0(int bx) { return (((bx & 7) * 24) + (bx >> 3)) * 4; }

__global__ __launch_bounds__(64) void k_scanA(
    const float* __restrict__ dt, const float* __restrict__ xdbl,
    const float* __restrict__ xi, const float* __restrict__ A_log,
    float* __restrict__ Hloc, float* __restrict__ Sdt) {
  int b = blockIdx.y, seg = blockIdx.z;
  int ch0 = scan_ch0(blockIdx.x);
  int tid = threadIdx.x;
  int c = tid >> 4, n = tid & 15;
  int d = ch0 + c;
  float a = -__expf(A_log[d * 16 + n]);
  float h = 0.f, sdt = 0.f;
  size_t row = (size_t)b * 2048 + seg * 64;
#pragma unroll 4
  for (int i = 0; i < 64; ++i, ++row) {
    float dtv = dt[row * 768 + d];
    float xiv = xi[row * 768 + d];
    float Bv = xdbl[row * 56 + 24 + n];
    float da = __expf(dtv * a);
    h = fmaf(da, h, dtv * Bv * xiv);
    sdt += dtv;
  }
  size_t o = (((size_t)b * 32 + seg) * 768 + d) * 16 + n;
  Hloc[o] = h;
  if (n == 0) Sdt[((size_t)b * 32 + seg) * 768 + d] = sdt;
}

__global__ __launch_bounds__(256) void k_scanB(
    const float* __restrict__ Hloc, const float* __restrict__ Sdt,
    const float* __restrict__ A_log, float* __restrict__ Hini) {
  int gid = blockIdx.x * 256 + threadIdx.x;
  if (gid >= 24576) return;
  int b = gid / 12288;
  int r = gid - b * 12288;
  int d = r >> 4, n = r & 15;
  float a = -__expf(A_log[d * 16 + n]);
  float h = 0.f;
  for (int s = 0; s < 32; ++s) {
    size_t o = (((size_t)b * 32 + s) * 768 + d) * 16 + n;
    Hini[o] = h;
    float P = __expf(a * Sdt[((size_t)b * 32 + s) * 768 + d]);
    h = fmaf(P, h, Hloc[o]);
  }
}

__global__ __launch_bounds__(64) void k_scanC(
    const float* __restrict__ dt, const float* __restrict__ xdbl,
    const float* __restrict__ xi, const float* __restrict__ xz,
    const float* __restrict__ A_log, const float* __restrict__ Dp,
    const float* __restrict__ Hini, u16* __restrict__ y) {
  __shared__ float s_y[64][4];
  int b = blockIdx.y, seg = blockIdx.z;
  int ch0 = scan_ch0(blockIdx.x);
  int tid = threadIdx.x;
  int c = tid >> 4, n = tid & 15;
  int d = ch0 + c;
  float a = -__expf(A_log[d * 16 + n]);
  float h = Hini[(((size_t)b * 32 + seg) * 768 + d) * 16 + n];
  size_t row = (size_t)b * 2048 + seg * 64;
#pragma unroll 2
  for (int i = 0; i < 64; ++i, ++row) {
    float dtv = dt[row * 768 + d];
    float xiv = xi[row * 768 + d];
    float Bv = xdbl[row * 56 + 24 + n];
    float Cv = xdbl[row * 56 + 40 + n];
    float da = __expf(dtv * a);
    h = fmaf(da, h, dtv * Bv * xiv);
    float yv = h * Cv;
    yv += __shfl_xor(yv, 1);
    yv += __shfl_xor(yv, 2);
    yv += __shfl_xor(yv, 4);
    yv += __shfl_xor(yv, 8);
    if (n == 0) s_y[i][c] = yv;
  }
  __syncthreads();
  size_t rw = (size_t)b * 2048 + seg * 64 + tid;
  f4 xiv4 = *(const f4*)(xi + rw * 768 + ch0);
  f4 dpv = *(const f4*)(Dp + ch0);
  f4 zv = *(const f4*)(xz + rw * 1536 + 768 + ch0);
  u16x4 ob;
#pragma unroll
  for (int e = 0; e < 4; ++e) {
    float o = (s_y[tid][e] + xiv4[e] * dpv[e]) * siluf(zv[e]);
    ob[e] = f2bf(o);
  }
  *(u16x4*)(y + rw * 768 + ch0) = ob;
}

// =====================================================================================
extern "C" void kernel_launch(void* const* d_in, const int* in_sizes, int n_in,
                              void* d_out, int out_size, void* d_ws, size_t ws_size,
                              hipStream_t stream) {
  const float* audio   = (const float*)d_in[0];
  const int*   tokens  = (const int*)d_in[1];
  const float* conv1_w = (const float*)d_in[2];
  const float* conv1_b = (const float*)d_in[3];
  const float* conv2_w = (const float*)d_in[4];
  const float* conv2_b = (const float*)d_in[5];
  const float* embedw  = (const float*)d_in[6];
  const float* P1[9], *P2[9];
  for (int i = 0; i < 9; ++i) { P1[i] = (const float*)d_in[7 + i]; P2[i] = (const float*)d_in[16 + i]; }
  const float* proj_w = (const float*)d_in[25];
  const float* proj_b = (const float*)d_in[26];
  (void)in_sizes; (void)n_in; (void)out_size; (void)ws_size;

  // ---- arena in d_out (fully overwritten by final GEMM) ----
  float* base = (float*)d_out;
  size_t off = 0;
  auto af = [&](size_t n) { float* p = base + off; off += n; return p; };
  float* xz   = af((size_t)4096 * 1536);
  float* xif  = af((size_t)4096 * 768);
  float* xdbl = af((size_t)4096 * 56);
  float* dtb  = af((size_t)4096 * 768);
  float* a1t  = af((size_t)2 * 1024 * 192);
  float* w1t  = af((size_t)80 * 3 * 192);
  float* w2t  = af((size_t)192 * 3 * 384);
  float* Hloc = af((size_t)2 * 32 * 768 * 16);
  float* Hini = af((size_t)2 * 32 * 768 * 16);
  float* Sdt  = af((size_t)2 * 32 * 768);
  u16* ub = (u16*)(base + off);
  size_t uoff = 0;
  auto au = [&](size_t n) { u16* p = ub + uoff; uoff += n; return p; };
  u16* Xin_b  = au((size_t)4096 * 384);
  u16* Xmid_b = au((size_t)4096 * 384);
  u16* xib    = au((size_t)4096 * 768);
  u16* xdblb  = au((size_t)4096 * 56);
  u16* yb16   = au((size_t)4096 * 768);
  u16* Wi1 = au((size_t)1536 * 384);
  u16* Wx1 = au((size_t)56 * 768);
  u16* Wd1 = au((size_t)768 * 32);
  u16* Wo1 = au((size_t)384 * 768);
  u16* Wi2 = au((size_t)1536 * 384);
  u16* Wx2 = au((size_t)56 * 768);
  u16* Wd2 = au((size_t)768 * 32);
  u16* Wo2 = au((size_t)384 * 768);
  u16* X2b    = (u16*)d_ws;                       // survive final GEMM's d_out writes
  u16* projwb = X2b + (size_t)4096 * 384;

  // ---- one batched weight-convert kernel ----
  CvtArgs ca;
  const float* srcs[9] = {P1[0], P1[3], P1[4], P1[8], P2[0], P2[3], P2[4], P2[8], proj_w};
  u16* dsts[9] = {Wi1, Wx1, Wd1, Wo1, Wi2, Wx2, Wd2, Wo2, projwb};
  int nqs[9] = {147456, 10752, 6144, 73728, 147456, 10752, 6144, 73728, 4824672};
  int cum = 0;
  for (int j = 0; j < 9; ++j) {
    ca.src[j] = srcs[j]; ca.dst[j] = dsts[j]; ca.nq[j] = nqs[j];
    ca.bstart[j] = cum; cum += (nqs[j] + 255) / 256;
  }
  ca.bstart[9] = cum;
  k_cvtmulti<<<dim3(cum), dim3(256), 0, stream>>>(ca);

  // ---- audio frontend + embedding -> Xin_b bf16 ----
  k_wtrans<<<dim3(180), dim3(256), 0, stream>>>(conv1_w, w1t, 192, 80);
  k_wtrans<<<dim3(864), dim3(256), 0, stream>>>(conv2_w, w2t, 384, 192);
  k_conv1<<<dim3(128), dim3(192), 0, stream>>>(audio, w1t, conv1_b, a1t);
  k_conv2b<<<dim3(256), dim3(384), 0, stream>>>(a1t, w2t, conv2_b, Xin_b);
  k_embedb<<<dim3(768), dim3(256), 0, stream>>>(tokens, embedw, Xin_b);

  auto run_mamba = [&](const float* const* P, const u16* Xin, u16* Xout,
                       const u16* Wi, const u16* Wx, const u16* Wd, const u16* Wo) {
    k_gemm2<64, 0, 0, 0, 1><<<dim3(64 * 24), dim3(256), 0, stream>>>(
        Xin, 384, Wi, 384, nullptr, xz, nullptr, 1536, 4096, 1536, 384);
    k_dwconv2<<<dim3(3072), dim3(256), 0, stream>>>(xz, P[1], P[2], xif, xib);
    k_gemm2<64, 0, 0, 2, 0><<<dim3(64 * 1), dim3(256), 0, stream>>>(
        xib, 768, Wx, 768, nullptr, xdbl, xdblb, 56, 4096, 56, 768);
    k_gemm2<64, 1, 1, 0, 0><<<dim3(64 * 12), dim3(256), 0, stream>>>(
        xdblb, 56, Wd, 32, P[5], dtb, nullptr, 768, 4096, 768, 32);
    k_scanA<<<dim3(192, 2, 32), dim3(64), 0, stream>>>(dtb, xdbl, xif, P[6], Hloc, Sdt);
    k_scanB<<<dim3(96), dim3(256), 0, stream>>>(Hloc, Sdt, P[6], Hini);
    k_scanC<<<dim3(192, 2, 32), dim3(64), 0, stream>>>(dtb, xdbl, xif, xz, P[6], P[7], Hini, yb16);
    k_gemm2<64, 0, 0, 1, 0><<<dim3(64 * 6), dim3(256), 0, stream>>>(
        yb16, 768, Wo, 768, nullptr, nullptr, Xout, 384, 4096, 384, 768);
  };
  run_mamba(P1, Xin_b, Xmid_b, Wi1, Wx1, Wd1, Wo1);
  run_mamba(P2, Xmid_b, X2b, Wi2, Wx2, Wd2, Wo2);

  // ---- final projection -> d_out [4096, 50257] f32 (BM64 x BN256, XCD-swizzled) ----
  k_gemmF<<<dim3(64 * 197), dim3(256), 0, stream>>>(
      X2b, 384, projwb, 384, proj_b, (float*)d_out, 50257, 4096, 50257, 384);
}